// Round 4
// baseline (544.646 us; speedup 1.0000x reference)
//
#include <hip/hip_runtime.h>
#include <math.h>

#define BB 64
#define NN 1024
#define CC 50
#define HH 512
#define KK 10
#define DP 64        // padded channel count for MFMA (d in [50,64) discarded)

typedef short bf16x8 __attribute__((ext_vector_type(8)));
typedef float f32x4  __attribute__((ext_vector_type(4)));

__device__ __forceinline__ float elu_f(float v) { return v > 0.f ? v : expm1f(v); }

// truncation split: f = hi + lo + eps, |eps| <= 2^-16 |f|
__device__ __forceinline__ void split_bf16(float f, unsigned short& hi, unsigned short& lo) {
    unsigned int u = __float_as_uint(f);
    hi = (unsigned short)(u >> 16);
    float hif = __uint_as_float(u & 0xFFFF0000u);
    lo = (unsigned short)(__float_as_uint(f - hif) >> 16);
}

// --------------------------------------------------------------------------
// K1: 32 blocks per batch, each owns 32 node rows (4 waves x 8 iters):
//   s[b,n]   = sum_m A[b,n,m] * x[b,m]          (wave dot, shfl reduce)
//   h1[c]    = elu(s * w1[c] + b1[c])
//   g[b,n,d] = sum_c h1[c] * w2[c,d]
// g is written SPLIT (bf16 hi/lo) and TRANSPOSED: Gt[b][d][n], so K2 can
// load MFMA B-fragments as single 16B reads. d in [50,64) left unwritten
// (poison) -- only feeds discarded output columns.
// --------------------------------------------------------------------------
__global__ __launch_bounds__(256) void k1_s_g(
        const float* __restrict__ x, const float* __restrict__ a,
        const float* __restrict__ w1, const float* __restrict__ b1,
        const float* __restrict__ w2,
        unsigned short* __restrict__ gt_hi, unsigned short* __restrict__ gt_lo)
{
    __shared__ float xs[NN];
    __shared__ float w1s[CC], b1s[CC];
    __shared__ float w2s[CC * CC];

    int tid = threadIdx.x;
    int b = blockIdx.x >> 5;            // 32 blocks per batch
    int seg = blockIdx.x & 31;          // rows [seg*32, seg*32+32)

    float4* xs4 = (float4*)xs;
    xs4[tid] = ((const float4*)(x + (size_t)b * NN))[tid];
    if (tid < CC) { w1s[tid] = w1[tid]; b1s[tid] = b1[tid]; }
    for (int i = tid; i < CC * CC; i += 256) w2s[i] = w2[i];
    __syncthreads();

    int wid = tid >> 6, lane = tid & 63;

    for (int it = 0; it < 8; ++it) {
        int n = seg * 32 + it * 4 + wid;
        const float4* arow = (const float4*)(a + ((size_t)b * NN + n) * NN);

        float acc = 0.f;
        #pragma unroll
        for (int k4 = 0; k4 < 4; ++k4) {
            float4 av = arow[k4 * 64 + lane];
            float4 xv = xs4[k4 * 64 + lane];
            acc += av.x * xv.x + av.y * xv.y + av.z * xv.z + av.w * xv.w;
        }
        #pragma unroll
        for (int off = 32; off; off >>= 1) acc += __shfl_xor(acc, off);
        // acc == s[b,n] in every lane

        float h1 = 0.f;
        if (lane < CC) h1 = elu_f(acc * w1s[lane] + b1s[lane]);

        float gacc = 0.f;
        #pragma unroll 10
        for (int c = 0; c < CC; ++c) {
            float hv = __shfl(h1, c);
            if (lane < CC) gacc += hv * w2s[c * CC + lane];
        }
        if (lane < CC) {
            unsigned short hi, lo;
            split_bf16(gacc, hi, lo);
            size_t off = ((size_t)b * DP + lane) * NN + n;  // [b][d][n]
            gt_hi[off] = hi;
            gt_lo[off] = lo;
        }
    }
}

// --------------------------------------------------------------------------
// K2 (MFMA): per batch: t[n,d] = sum_m A[b,n,m]*g[b,m,d] via split-bf16:
//   t = A_hi@G_hi + A_hi@G_lo + A_lo@G_hi   (fp32 accumulate, err ~2^-15)
// Then pooled[b,d] += sum_n elu(t + b2[d]).
// 8 blocks/batch (128 rows each), 4 waves/block (32 rows each).
// A-fragments: direct global->register (each A element used exactly once),
// converted in-register. B-fragments: 16B loads from Gt (L2/L3-hot).
// mfma_f32_16x16x32_bf16 layouts (m89/m91-verified D; standard A/B):
//   A: lane l holds A[l&15][8*(l>>4)+j]   B: lane l holds B[8*(l>>4)+j][l&15]
//   D: lane l holds D[4*(l>>4)+j][l&15]
// Reverse batch order: A is LLC-resident from K1's forward stream.
// --------------------------------------------------------------------------
__global__ __launch_bounds__(256) void k2_mfma_pool(
        const float* __restrict__ a,
        const unsigned short* __restrict__ gt_hi,
        const unsigned short* __restrict__ gt_lo,
        const float* __restrict__ b2, float* __restrict__ pooled)
{
    __shared__ float ps[DP];

    int tid = threadIdx.x;
    int wv = tid >> 6, l = tid & 63;
    int lr = l & 15, lk = l >> 4;
    int b  = (BB - 1) - (blockIdx.x >> 3);   // reverse order for LLC reuse
    int n0 = (blockIdx.x & 7) * 128 + wv * 32;

    const float* Ab = a + ((size_t)b * NN + n0) * NN;
    const unsigned short* Gh = gt_hi + (size_t)b * DP * NN;
    const unsigned short* Gl = gt_lo + (size_t)b * DP * NN;

    if (tid < DP) ps[tid] = 0.f;

    float bias[4];
    #pragma unroll
    for (int ds = 0; ds < 4; ++ds) {
        int d = ds * 16 + lr;
        bias[ds] = (d < CC) ? b2[d] : 0.f;
    }

    f32x4 acc[2][4] = {};   // [n-subtile][d-subtile]

    for (int m0 = 0; m0 < NN; m0 += 32) {
        // ---- A fragments: load 8 fp32, split to bf16 hi/lo in-register ----
        bf16x8 ah[2], al[2];
        #pragma unroll
        for (int s = 0; s < 2; ++s) {
            const float* ap = Ab + (size_t)(s * 16 + lr) * NN + m0 + lk * 8;
            float4 v0 = *(const float4*)(ap);
            float4 v1 = *(const float4*)(ap + 4);
            float av[8] = {v0.x, v0.y, v0.z, v0.w, v1.x, v1.y, v1.z, v1.w};
            #pragma unroll
            for (int j = 0; j < 8; ++j) {
                unsigned short hi, lo;
                split_bf16(av[j], hi, lo);
                ah[s][j] = (short)hi;
                al[s][j] = (short)lo;
            }
        }
        // ---- B fragments: Gt[d][m], 8 contiguous bf16 = one 16B load ----
        bf16x8 bh[4], bl[4];
        #pragma unroll
        for (int ds = 0; ds < 4; ++ds) {
            size_t off = (size_t)(ds * 16 + lr) * NN + m0 + lk * 8;
            bh[ds] = *(const bf16x8*)(Gh + off);
            bl[ds] = *(const bf16x8*)(Gl + off);
        }
        // ---- 3-product split MFMA ----
        #pragma unroll
        for (int s = 0; s < 2; ++s)
            #pragma unroll
            for (int ds = 0; ds < 4; ++ds) {
                acc[s][ds] = __builtin_amdgcn_mfma_f32_16x16x32_bf16(ah[s], bh[ds], acc[s][ds], 0, 0, 0);
                acc[s][ds] = __builtin_amdgcn_mfma_f32_16x16x32_bf16(ah[s], bl[ds], acc[s][ds], 0, 0, 0);
                acc[s][ds] = __builtin_amdgcn_mfma_f32_16x16x32_bf16(al[s], bh[ds], acc[s][ds], 0, 0, 0);
            }
    }

    __syncthreads();   // ps initialized
    // epilogue: elu(t + b2), sum over this wave's 8 n-rows per (lane,ds),
    // then reduce the 4 lane-groups sharing the same d (l, l^16, l^32, l^48).
    #pragma unroll
    for (int ds = 0; ds < 4; ++ds) {
        int d = ds * 16 + lr;
        float s = 0.f;
        if (d < CC) {
            #pragma unroll
            for (int sb = 0; sb < 2; ++sb)
                #pragma unroll
                for (int j = 0; j < 4; ++j)
                    s += elu_f(acc[sb][ds][j] + bias[ds]);
        }
        s += __shfl_xor(s, 16);
        s += __shfl_xor(s, 32);
        if (lk == 0 && d < CC) atomicAdd(&ps[d], s);
    }
    __syncthreads();
    if (tid < CC) atomicAdd(&pooled[b * CC + tid], ps[tid]);
}

// --------------------------------------------------------------------------
// K3: pooled[b,:] -> relu(fc1) -> softmax(fc2). One block per batch row.
// --------------------------------------------------------------------------
__global__ __launch_bounds__(256) void k3_fc(
        const float* __restrict__ pooled,
        const float* __restrict__ wf1, const float* __restrict__ bf1,
        const float* __restrict__ wf2, const float* __restrict__ bf2,
        float* __restrict__ out)
{
    __shared__ float p[CC];
    __shared__ float h[HH];
    __shared__ float lg[KK];
    int b = blockIdx.x, tid = threadIdx.x;

    if (tid < CC) p[tid] = pooled[b * CC + tid];
    __syncthreads();

    for (int j = tid; j < HH; j += 256) {
        float acc = bf1[j];
        #pragma unroll 10
        for (int c = 0; c < CC; ++c) acc += p[c] * wf1[c * HH + j];
        h[j] = fmaxf(acc, 0.f);
    }
    __syncthreads();

    if (tid < KK) {
        float acc = bf2[tid];
        for (int j = 0; j < HH; ++j) acc += h[j] * wf2[j * KK + tid];
        lg[tid] = acc;
    }
    __syncthreads();

    if (tid == 0) {
        float mx = lg[0];
        for (int k = 1; k < KK; ++k) mx = fmaxf(mx, lg[k]);
        float e[KK], sum = 0.f;
        for (int k = 0; k < KK; ++k) { e[k] = expf(lg[k] - mx); sum += e[k]; }
        float inv = 1.f / sum;
        for (int k = 0; k < KK; ++k) out[b * KK + k] = e[k] * inv;
    }
}

extern "C" void kernel_launch(void* const* d_in, const int* in_sizes, int n_in,
                              void* d_out, int out_size, void* d_ws, size_t ws_size,
                              hipStream_t stream) {
    const float* x   = (const float*)d_in[0];
    const float* a   = (const float*)d_in[1];
    const float* w1  = (const float*)d_in[2];
    const float* b1  = (const float*)d_in[3];
    const float* w2  = (const float*)d_in[4];
    const float* b2  = (const float*)d_in[5];
    const float* wf1 = (const float*)d_in[6];
    const float* bf1 = (const float*)d_in[7];
    const float* wf2 = (const float*)d_in[8];
    const float* bf2 = (const float*)d_in[9];
    float* out = (float*)d_out;

    // workspace layout:
    //   [0, 64KB)          pooled   (64*50 f32)
    //   [64KB, 64KB+8MB)   gt_hi    (64*64*1024 bf16)
    //   [+8MB, +16MB)      gt_lo
    float*          pooled = (float*)d_ws;
    unsigned short* gt_hi  = (unsigned short*)((char*)d_ws + (64 << 10));
    unsigned short* gt_lo  = (unsigned short*)((char*)d_ws + (64 << 10) + ((size_t)BB * DP * NN * 2));

    hipMemsetAsync(pooled, 0, BB * CC * sizeof(float), stream);
    k1_s_g<<<BB * 32, 256, 0, stream>>>(x, a, w1, b1, w2, gt_hi, gt_lo);
    k2_mfma_pool<<<BB * 8, 256, 0, stream>>>(a, gt_hi, gt_lo, b2, pooled);
    k3_fc<<<BB, 256, 0, stream>>>(pooled, wf1, bf1, wf2, bf2, out);
}